// Round 5
// baseline (718.833 us; speedup 1.0000x reference)
//
#include <hip/hip_runtime.h>

#define N_PTS 200000
#define GRIDL 192
#define CAP 8192            // per-tap bin capacity (mean ~5651)
#define NREG 216            // 6^3 regions of 32^3 cells
#define RCAP 1152           // per-region point capacity (mean ~926, sigma ~30)
#define NSLICE 9            // enum: 9 slices of 128 points cover RCAP
#define HMAX 16             // per-point hit cap (Poisson mean 2.26; P(>16) ~ 3e-10)
#define HCAP_TOT 524288     // total staging slots (expected ~452K)

// ---- workspace layout (bytes), identical to R4 ----
#define VOL_OFF   0ull
#define VOL_BYTES (192ull*192ull*192ull*4ull)   // 28,311,552
#define BINS_OFF  28311552ull                   // 125*8192*8 = 8,192,000
#define BCNT_OFF  36503552ull                   // 125*32*4 = 16,000 (128B-padded)
#define GCUR_OFF  36519552ull                   // 128
#define RCNT_OFF  36519680ull                   // 216*32*4 = 27,648 (128B-padded)
#define PLIST_OFF 36547328ull                   // 216*1152*8 = 1,990,656
#define WBUF_OFF  38537984ull                   // 125*2304*4 = 1,152,000
#define VTAB_OFF  39689984ull                   // 125*16 = 2,000
#define A0_OFF    39691984ull                   // 4,096
#define A1_OFF    39696080ull                   // 1,024
#define HDR_OFF   39697104ull                   // 200,000*8 = 1,600,000
#define STAGE_OFF 41297104ull                   // 524,288*320 = 167,772,160
#define WS_NEED   (STAGE_OFF + (unsigned long long)HCAP_TOT * 320ull)  // ~209 MB

// 80 live taps (1 <= ||off||^2 <= 6)
struct TapTable { int p[80]; };
__host__ __device__ constexpr TapTable make_taps() {
    TapTable tt{}; int t = 0;
    for (int a = -2; a <= 2; a++)
        for (int b = -2; b <= 2; b++)
            for (int c = -2; c <= 2; c++) {
                int sq = a*a + b*b + c*c;
                if (sq >= 1 && sq <= 6) tt.p[t++] = (a+2)*25 + (b+2)*5 + (c+2);
            }
    return tt;
}
__device__ const TapTable TAPS = make_taps();

// ============================================================
// Kernel 1: build scaled structured weights + fused sc matrices
// ============================================================
__global__ void prep_kernel(const float* __restrict__ wt, const float* __restrict__ wsc0,
                            const float* __restrict__ wsc1, float* __restrict__ wbuf,
                            float* __restrict__ vtab, float* __restrict__ A0,
                            float* __restrict__ A1) {
    int p = blockIdx.x;
    int dx = p / 25 - 2, dy = (p / 5) % 5 - 2, dz = p % 5 - 2;
    double d = sqrt((double)(dx*dx + dy*dy + dz*dz));
    const double step = 2.5 / 9.0;
    const double cst = 1.14136 * exp(2.0);
    float emb[8];
#pragma unroll
    for (int r = 0; r < 8; r++) {
        double t = (d - (double)(r + 1) * step) / step;
        double tt = t * t;
        emb[r] = (tt < 1.0) ? (float)(cst * exp(-2.0 / (1.0 - tt))) : 0.0f;
    }
    if (threadIdx.x == 0) {
        float inv = (d > 0.0) ? (float)(sqrt(3.0) / d) : 0.0f;
        vtab[p*4+0] = dx * inv; vtab[p*4+1] = dy * inv;
        vtab[p*4+2] = dz * inv; vtab[p*4+3] = 0.0f;
    }
    const float ALPHA = 0.14433756729740643f;   // 1/sqrt(48)
    for (int q = threadIdx.x; q < 2304; q += blockDim.x) {
        float acc = 0.0f;
#pragma unroll
        for (int r = 0; r < 8; r++) acc = fmaf(emb[r], wt[r*2304 + q], acc);
        acc *= (1.0f / 125.0f);
        float val = acc * ((q < 1792) ? ALPHA : (1.0f / 12.0f));
        wbuf[p*2304 + q] = val;
        if (p == 62) {  // center tap: val==0 (EMB(0)=0); fold sc matrices
            if (q < 1024)                   A0[q]        = wsc0[q] * 0.17677669529663687f + val;
            else if (q >= 1536 && q < 1792) A1[q-1536]   = wsc1[q-1536] * 0.25f + val;
        }
    }
}

// ============================================================
// Kernel 2: scatter (two-pass LDS histogram, padded global atomics)
// ============================================================
__global__ __launch_bounds__(256) void scatter_kernel(const int* __restrict__ coords,
        int* __restrict__ vol, int* __restrict__ rcnt_pad, int2* __restrict__ plist) {
    __shared__ int hist[216];
    __shared__ int rbase[216];
    for (int i = threadIdx.x; i < 216; i += 256) hist[i] = 0;
    __syncthreads();
    for (int n = blockIdx.x * 256 + threadIdx.x; n < N_PTS; n += 65536) {
        int x = coords[n*3], y = coords[n*3+1], z = coords[n*3+2];
        vol[(x * GRIDL + y) * GRIDL + z] = n;
        int r = (x >> 5) * 36 + (y >> 5) * 6 + (z >> 5);
        atomicAdd(&hist[r], 1);
    }
    __syncthreads();
    if (threadIdx.x < 216) {
        int c = hist[threadIdx.x];
        rbase[threadIdx.x] = c ? atomicAdd(&rcnt_pad[threadIdx.x * 32], c) : 0;
        hist[threadIdx.x] = 0;   // reuse as cursor
    }
    __syncthreads();
    for (int n = blockIdx.x * 256 + threadIdx.x; n < N_PTS; n += 65536) {
        int x = coords[n*3], y = coords[n*3+1], z = coords[n*3+2];
        int r = (x >> 5) * 36 + (y >> 5) * 6 + (z >> 5);
        int j = rbase[r] + atomicAdd(&hist[r], 1);
        if (j < RCAP) plist[r * RCAP + j] = make_int2(n, (x << 16) | (y << 8) | z);
    }
}

// ============================================================
// Kernel 3: enumerate hits. Grid 216*NSLICE blocks of 128 threads; each
// block takes a 128-point slice of one region. Hits packed (t<<18)|nb in
// 8KB LDS; block allocator assigns destination-contiguous staging slots
// (1 gcur atomic/block); per-tap reservation via padded bcnt atomics;
// bins written directly with scattered 8B stores.
// STG: bins carry (slot, nb), hdr[n]=(base,cnt).  !STG: bins carry (n, nb).
// ============================================================
template<bool STG>
__global__ __launch_bounds__(128) void enum_kernel(const int* __restrict__ vol,
        const int* __restrict__ rcnt_pad, const int2* __restrict__ plist,
        int* __restrict__ bcnt_pad, int2* __restrict__ bins,
        int2* __restrict__ hdr, int* __restrict__ gcur) {
    int r = blockIdx.x / NSLICE, s = blockIdx.x % NSLICE;
    int cnt = min(rcnt_pad[r * 32], RCAP);
    int lo = s * 128, hi = min(cnt, lo + 128);
    if (lo >= hi) return;                      // block-uniform exit
    __shared__ int hist[80];
    __shared__ int tbase[80];
    __shared__ int cursor[80];
    __shared__ int mh[128 * HMAX];             // packed (t<<18)|nb, 8 KB
    __shared__ int blockTot, gbase_s;
    if (threadIdx.x < 80) { hist[threadIdx.x] = 0; cursor[threadIdx.x] = 0; }
    __syncthreads();

    int idx = lo + threadIdx.x;
    bool act = idx < hi;
    int n = -1, x = 0, y = 0, z = 0;
    if (act) {
        int2 e = plist[r * RCAP + idx];
        n = e.x; x = e.y >> 16; y = (e.y >> 8) & 255; z = e.y & 255;
    }
    int myc = 0;
    int t = 0;
#pragma unroll
    for (int a = -2; a <= 2; a++)
#pragma unroll
    for (int b = -2; b <= 2; b++)
#pragma unroll
    for (int c = -2; c <= 2; c++) {
        int sq = a*a + b*b + c*c;
        if (sq < 1 || sq > 6) continue;        // dead tap: K==0
        int cx = x + a, cy = y + b, cz = z + c;
        if (act && ((unsigned)cx < 192u) && ((unsigned)cy < 192u) && ((unsigned)cz < 192u)) {
            int nb = vol[(cx * GRIDL + cy) * GRIDL + cz];
            if (nb >= 0 && myc < HMAX) {
                mh[threadIdx.x * HMAX + myc] = (t << 18) | nb;
                myc++;
                atomicAdd(&hist[t], 1);
            }
        }
        t++;
    }
    __syncthreads();

    int sbase = 0, cn = myc;
    if (STG) {
        if (threadIdx.x == 0) blockTot = 0;
        __syncthreads();
        int lbase = atomicAdd(&blockTot, myc);
        __syncthreads();
        if (threadIdx.x == 0) gbase_s = atomicAdd(gcur, blockTot);
        __syncthreads();
        sbase = gbase_s + lbase;
        int avail = HCAP_TOT - sbase;
        cn = min(myc, max(avail, 0));
        if (act) hdr[n] = make_int2(sbase, cn);
    }
    if (threadIdx.x < 80)
        tbase[threadIdx.x] = hist[threadIdx.x]
            ? atomicAdd(&bcnt_pad[TAPS.p[threadIdx.x] * 32], hist[threadIdx.x]) : 0;
    __syncthreads();

    for (int j = 0; j < cn; j++) {
        int e = mh[threadIdx.x * HMAX + j];
        int tt = e >> 18, nb = e & 0x3FFFF;
        int k = atomicAdd(&cursor[tt], 1);
        int pos = tbase[tt] + k;
        if (pos < CAP)
            bins[TAPS.p[tt] * CAP + pos] = make_int2(STG ? (sbase + j) : n, nb);
    }
}

// ============================================================
// Kernel 4 (fallback only): out[n] = sc(feats[n])
// ============================================================
__global__ __launch_bounds__(256) void sc_self_kernel(const float* __restrict__ feats,
        const float* __restrict__ A0, const float* __restrict__ A1,
        float* __restrict__ out) {
    __shared__ __align__(16) float sA0[1024];
    __shared__ __align__(16) float sA1[256];
    for (int i = threadIdx.x; i < 1024; i += 256) sA0[i] = A0[i];
    if (threadIdx.x < 256) sA1[threadIdx.x] = A1[threadIdx.x];
    __syncthreads();
    int n = blockIdx.x * 256 + threadIdx.x;
    if (n >= N_PTS) return;
    const float4* fr = (const float4*)(feats + (size_t)n * 80);
    float4* orow = (float4*)(out + (size_t)n * 80);
    float f0[32];
#pragma unroll
    for (int j = 0; j < 8; j++) {
        float4 t = fr[j];
        f0[4*j] = t.x; f0[4*j+1] = t.y; f0[4*j+2] = t.z; f0[4*j+3] = t.w;
    }
    float a0[32];
#pragma unroll
    for (int k = 0; k < 32; k++) a0[k] = 0.0f;
#pragma unroll
    for (int i = 0; i < 32; i++) {
        float fv = f0[i];
#pragma unroll
        for (int k4 = 0; k4 < 8; k4++) {
            float4 w = ((const float4*)sA0)[i*8 + k4];
            a0[4*k4]   = fmaf(fv, w.x, a0[4*k4]);
            a0[4*k4+1] = fmaf(fv, w.y, a0[4*k4+1]);
            a0[4*k4+2] = fmaf(fv, w.z, a0[4*k4+2]);
            a0[4*k4+3] = fmaf(fv, w.w, a0[4*k4+3]);
        }
    }
#pragma unroll
    for (int j = 0; j < 8; j++) orow[j] = make_float4(a0[4*j], a0[4*j+1], a0[4*j+2], a0[4*j+3]);
    float f1[48];
#pragma unroll
    for (int j = 0; j < 12; j++) {
        float4 t = fr[8 + j];
        f1[4*j] = t.x; f1[4*j+1] = t.y; f1[4*j+2] = t.z; f1[4*j+3] = t.w;
    }
    float a1[48];
#pragma unroll
    for (int k = 0; k < 48; k++) a1[k] = 0.0f;
#pragma unroll
    for (int i = 0; i < 16; i++) {
        float fm0 = f1[3*i], fm1 = f1[3*i+1], fm2 = f1[3*i+2];
#pragma unroll
        for (int k4 = 0; k4 < 4; k4++) {
            float4 w = ((const float4*)sA1)[i*4 + k4];
            const float* wp = (const float*)&w;
#pragma unroll
            for (int kk = 0; kk < 4; kk++) {
                int k = 4*k4 + kk;
                a1[3*k]   = fmaf(fm0, wp[kk], a1[3*k]);
                a1[3*k+1] = fmaf(fm1, wp[kk], a1[3*k+1]);
                a1[3*k+2] = fmaf(fm2, wp[kk], a1[3*k+2]);
            }
        }
    }
#pragma unroll
    for (int j = 0; j < 12; j++) orow[8+j] = make_float4(a1[4*j], a1[4*j+1], a1[4*j+2], a1[4*j+3]);
}

// ============================================================
// Kernel 5: per-tap structured apply. No LDS transpose, no inner barriers:
// each lane streams its own contiguous 320B row (STG: plain stores into
// staging; !STG: row atomics into out). LDS = 9.2KB weights only.
// ============================================================
template<bool STG>
__global__ __launch_bounds__(128) void bin_kernel(const float* __restrict__ feats,
        const float* __restrict__ wbuf, const float* __restrict__ vtab,
        const int* __restrict__ bcnt_pad, const int2* __restrict__ bins,
        float* __restrict__ stg, float* __restrict__ out) {
    int p = blockIdx.x >> 4;
    int chunk = blockIdx.x & 15;
    int cnt = min(bcnt_pad[p * 32], CAP);
    int start = chunk * 512;
    if (start >= cnt) return;

    __shared__ __align__(16) float sW[2304];
    __shared__ float sv[4];
    for (int i = threadIdx.x; i < 2304; i += 128) sW[i] = wbuf[p*2304 + i];
    if (threadIdx.x < 4) sv[threadIdx.x] = vtab[p*4 + threadIdx.x];
    __syncthreads();

    const float4* sW1 = (const float4*)sW;            // [32][8]
    const float4* sW2 = (const float4*)(sW + 1024);   // [32][4]
    const float4* sW3 = (const float4*)(sW + 1536);   // [16][4]
    const float4* sW4 = (const float4*)(sW + 1792);   // [16][8]
    float v0 = sv[0], v1 = sv[1], v2 = sv[2];

    for (int it = 0; it < 4; it++) {
        int h = start + it * 128 + threadIdx.x;
        if (h >= cnt) break;
        int2 e = bins[p*CAP + h];
        int d = e.x, nb = e.y;

        const float4* fr = (const float4*)(feats + (size_t)nb * 80);
        float f0[32], f1[48];
#pragma unroll
        for (int j = 0; j < 8; j++) {
            float4 t = fr[j];
            f0[4*j] = t.x; f0[4*j+1] = t.y; f0[4*j+2] = t.z; f0[4*j+3] = t.w;
        }
#pragma unroll
        for (int j = 0; j < 12; j++) {
            float4 t = fr[8 + j];
            f1[4*j] = t.x; f1[4*j+1] = t.y; f1[4*j+2] = t.z; f1[4*j+3] = t.w;
        }
        float g[16];
#pragma unroll
        for (int i = 0; i < 16; i++)
            g[i] = f1[3*i]*v0 + f1[3*i+1]*v1 + f1[3*i+2]*v2;

        float a0[32], cc[16];
#pragma unroll
        for (int k = 0; k < 32; k++) a0[k] = 0.0f;
#pragma unroll
        for (int k = 0; k < 16; k++) cc[k] = 0.0f;
#pragma unroll
        for (int i = 0; i < 32; i++) {
            float fv = f0[i];
#pragma unroll
            for (int k4 = 0; k4 < 8; k4++) {
                float4 w = sW1[i*8 + k4];
                a0[4*k4]   = fmaf(fv, w.x, a0[4*k4]);
                a0[4*k4+1] = fmaf(fv, w.y, a0[4*k4+1]);
                a0[4*k4+2] = fmaf(fv, w.z, a0[4*k4+2]);
                a0[4*k4+3] = fmaf(fv, w.w, a0[4*k4+3]);
            }
#pragma unroll
            for (int k4 = 0; k4 < 4; k4++) {
                float4 w = sW2[i*4 + k4];
                cc[4*k4]   = fmaf(fv, w.x, cc[4*k4]);
                cc[4*k4+1] = fmaf(fv, w.y, cc[4*k4+1]);
                cc[4*k4+2] = fmaf(fv, w.z, cc[4*k4+2]);
                cc[4*k4+3] = fmaf(fv, w.w, cc[4*k4+3]);
            }
        }
#pragma unroll
        for (int i = 0; i < 16; i++) {
            float gv = g[i];
#pragma unroll
            for (int k4 = 0; k4 < 8; k4++) {
                float4 w = sW4[i*8 + k4];
                a0[4*k4]   = fmaf(gv, w.x, a0[4*k4]);
                a0[4*k4+1] = fmaf(gv, w.y, a0[4*k4+1]);
                a0[4*k4+2] = fmaf(gv, w.z, a0[4*k4+2]);
                a0[4*k4+3] = fmaf(gv, w.w, a0[4*k4+3]);
            }
        }
        // flush a0 early to shorten live ranges
        if (STG) {
            float4* row = (float4*)(stg + (size_t)d * 80);
#pragma unroll
            for (int j = 0; j < 8; j++)
                row[j] = make_float4(a0[4*j], a0[4*j+1], a0[4*j+2], a0[4*j+3]);
        } else {
            float* orow = out + (size_t)d * 80;
#pragma unroll
            for (int k = 0; k < 32; k++) unsafeAtomicAdd(orow + k, a0[k]);
        }

        float a1[48];
#pragma unroll
        for (int k = 0; k < 16; k++) {
            a1[3*k] = v0 * cc[k]; a1[3*k+1] = v1 * cc[k]; a1[3*k+2] = v2 * cc[k];
        }
#pragma unroll
        for (int i = 0; i < 16; i++) {
            float fm0 = f1[3*i], fm1 = f1[3*i+1], fm2 = f1[3*i+2];
#pragma unroll
            for (int k4 = 0; k4 < 4; k4++) {
                float4 w = sW3[i*4 + k4];
                const float* wp = (const float*)&w;
#pragma unroll
                for (int kk = 0; kk < 4; kk++) {
                    int k = 4*k4 + kk;
                    a1[3*k]   = fmaf(fm0, wp[kk], a1[3*k]);
                    a1[3*k+1] = fmaf(fm1, wp[kk], a1[3*k+1]);
                    a1[3*k+2] = fmaf(fm2, wp[kk], a1[3*k+2]);
                }
            }
        }
        if (STG) {
            float4* row = (float4*)(stg + (size_t)d * 80);
#pragma unroll
            for (int j = 0; j < 12; j++)
                row[8+j] = make_float4(a1[4*j], a1[4*j+1], a1[4*j+2], a1[4*j+3]);
        } else {
            float* orow = out + (size_t)d * 80;
#pragma unroll
            for (int k = 0; k < 48; k++) unsafeAtomicAdd(orow + 32 + k, a1[k]);
        }
    }
}

// ============================================================
// Kernel 6 (STG only): out[n] = sc(feats[n]) + sum of n's staging rows
// ============================================================
__global__ __launch_bounds__(256) void gather_kernel(const float* __restrict__ feats,
        const float* __restrict__ A0, const float* __restrict__ A1,
        const int2* __restrict__ hdr, const float* __restrict__ stg,
        float* __restrict__ out) {
    __shared__ __align__(16) float sA0[1024];
    __shared__ __align__(16) float sA1[256];
    for (int i = threadIdx.x; i < 1024; i += 256) sA0[i] = A0[i];
    if (threadIdx.x < 256) sA1[threadIdx.x] = A1[threadIdx.x];
    __syncthreads();
    int n = blockIdx.x * 256 + threadIdx.x;
    if (n >= N_PTS) return;
    int2 h = hdr[n];
    const float4* fr = (const float4*)(feats + (size_t)n * 80);
    float a0[32], a1[48];
    {
        float f0[32];
#pragma unroll
        for (int j = 0; j < 8; j++) {
            float4 t = fr[j];
            f0[4*j] = t.x; f0[4*j+1] = t.y; f0[4*j+2] = t.z; f0[4*j+3] = t.w;
        }
#pragma unroll
        for (int k = 0; k < 32; k++) a0[k] = 0.0f;
#pragma unroll
        for (int i = 0; i < 32; i++) {
            float fv = f0[i];
#pragma unroll
            for (int k4 = 0; k4 < 8; k4++) {
                float4 w = ((const float4*)sA0)[i*8 + k4];
                a0[4*k4]   = fmaf(fv, w.x, a0[4*k4]);
                a0[4*k4+1] = fmaf(fv, w.y, a0[4*k4+1]);
                a0[4*k4+2] = fmaf(fv, w.z, a0[4*k4+2]);
                a0[4*k4+3] = fmaf(fv, w.w, a0[4*k4+3]);
            }
        }
        float f1[48];
#pragma unroll
        for (int j = 0; j < 12; j++) {
            float4 t = fr[8 + j];
            f1[4*j] = t.x; f1[4*j+1] = t.y; f1[4*j+2] = t.z; f1[4*j+3] = t.w;
        }
#pragma unroll
        for (int k = 0; k < 48; k++) a1[k] = 0.0f;
#pragma unroll
        for (int i = 0; i < 16; i++) {
            float fm0 = f1[3*i], fm1 = f1[3*i+1], fm2 = f1[3*i+2];
#pragma unroll
            for (int k4 = 0; k4 < 4; k4++) {
                float4 w = ((const float4*)sA1)[i*4 + k4];
                const float* wp = (const float*)&w;
#pragma unroll
                for (int kk = 0; kk < 4; kk++) {
                    int k = 4*k4 + kk;
                    a1[3*k]   = fmaf(fm0, wp[kk], a1[3*k]);
                    a1[3*k+1] = fmaf(fm1, wp[kk], a1[3*k+1]);
                    a1[3*k+2] = fmaf(fm2, wp[kk], a1[3*k+2]);
                }
            }
        }
    }
    for (int j = 0; j < h.y; j++) {
        const float4* rp = (const float4*)(stg + (size_t)(h.x + j) * 80);
#pragma unroll
        for (int q = 0; q < 8; q++) {
            float4 t = rp[q];
            a0[4*q] += t.x; a0[4*q+1] += t.y; a0[4*q+2] += t.z; a0[4*q+3] += t.w;
        }
#pragma unroll
        for (int q = 0; q < 12; q++) {
            float4 t = rp[8 + q];
            a1[4*q] += t.x; a1[4*q+1] += t.y; a1[4*q+2] += t.z; a1[4*q+3] += t.w;
        }
    }
    float4* orow = (float4*)(out + (size_t)n * 80);
#pragma unroll
    for (int j = 0; j < 8; j++)  orow[j]   = make_float4(a0[4*j], a0[4*j+1], a0[4*j+2], a0[4*j+3]);
#pragma unroll
    for (int j = 0; j < 12; j++) orow[8+j] = make_float4(a1[4*j], a1[4*j+1], a1[4*j+2], a1[4*j+3]);
}

extern "C" void kernel_launch(void* const* d_in, const int* in_sizes, int n_in,
                              void* d_out, int out_size, void* d_ws, size_t ws_size,
                              hipStream_t stream) {
    const float* feats = (const float*)d_in[0];
    const float* wt    = (const float*)d_in[1];
    const float* wsc0  = (const float*)d_in[2];
    const float* wsc1  = (const float*)d_in[3];
    const int*   coords= (const int*)d_in[4];
    float* out = (float*)d_out;
    char* ws = (char*)d_ws;

    int*   vol      = (int*)(ws + VOL_OFF);
    int2*  bins     = (int2*)(ws + BINS_OFF);
    int*   bcnt_pad = (int*)(ws + BCNT_OFF);
    int*   gcur     = (int*)(ws + GCUR_OFF);
    int*   rcnt_pad = (int*)(ws + RCNT_OFF);
    int2*  plist    = (int2*)(ws + PLIST_OFF);
    float* wbuf     = (float*)(ws + WBUF_OFF);
    float* vtab     = (float*)(ws + VTAB_OFF);
    float* A0       = (float*)(ws + A0_OFF);
    float* A1       = (float*)(ws + A1_OFF);
    int2*  hdr      = (int2*)(ws + HDR_OFF);
    float* stg      = (float*)(ws + STAGE_OFF);

    bool staging = (unsigned long long)ws_size >= WS_NEED;   // constant across calls

    hipMemsetAsync(vol, 0xFF, VOL_BYTES, stream);            // -1 everywhere
    hipMemsetAsync(bcnt_pad, 0, 16000 + 128 + 27648, stream);// bcnt + gcur + rcnt

    prep_kernel<<<125, 256, 0, stream>>>(wt, wsc0, wsc1, wbuf, vtab, A0, A1);
    scatter_kernel<<<256, 256, 0, stream>>>(coords, vol, rcnt_pad, plist);
    if (staging) {
        enum_kernel<true><<<NREG * NSLICE, 128, 0, stream>>>(vol, rcnt_pad, plist, bcnt_pad, bins, hdr, gcur);
        bin_kernel<true><<<125 * 16, 128, 0, stream>>>(feats, wbuf, vtab, bcnt_pad, bins, stg, out);
        gather_kernel<<<(N_PTS + 255) / 256, 256, 0, stream>>>(feats, A0, A1, hdr, stg, out);
    } else {
        enum_kernel<false><<<NREG * NSLICE, 128, 0, stream>>>(vol, rcnt_pad, plist, bcnt_pad, bins, hdr, gcur);
        sc_self_kernel<<<(N_PTS + 255) / 256, 256, 0, stream>>>(feats, A0, A1, out);
        bin_kernel<false><<<125 * 16, 128, 0, stream>>>(feats, wbuf, vtab, bcnt_pad, bins, stg, out);
    }
}

// Round 6
// 500.828 us; speedup vs baseline: 1.4353x; 1.4353x over previous
//
#include <hip/hip_runtime.h>

#define N_PTS 200000
#define GRIDL 192
#define CAP 8192            // per-tap bin capacity (mean ~5651)
#define NREG 216            // 6^3 regions of 32^3 cells
#define RCAP 1152           // per-region point capacity (mean ~926, sigma ~30)
#define NSLICE 9            // enum: 9 slices of 128 points cover RCAP
#define SCAP 32             // per-(slice,tap) LDS stage (mean 5.6; P(>32) ~ 1e-16)

// ---- workspace layout (bytes), all 16-aligned; ~39.7 MB total ----
#define VOL_OFF   0ull
#define VOL_BYTES (192ull*192ull*192ull*4ull)   // 28,311,552
#define BINS_OFF  28311552ull                   // 125*8192*8 = 8,192,000
#define BCNT_OFF  36503552ull                   // 125*32*4 = 16,000 (128B-padded)
#define RCNT_OFF  36519552ull                   // 216*32*4 = 27,648 (128B-padded)
#define PLIST_OFF 36547200ull                   // 216*1152*8 = 1,990,656
#define WBUF_OFF  38537856ull                   // 125*2304*4 = 1,152,000
#define VTAB_OFF  39689856ull                   // 125*16 = 2,000
#define A0_OFF    39691856ull                   // 4,096
#define A1_OFF    39695952ull                   // 1,024

// 80 live taps (1 <= ||off||^2 <= 6)
struct TapTable { int p[80]; };
__host__ __device__ constexpr TapTable make_taps() {
    TapTable tt{}; int t = 0;
    for (int a = -2; a <= 2; a++)
        for (int b = -2; b <= 2; b++)
            for (int c = -2; c <= 2; c++) {
                int sq = a*a + b*b + c*c;
                if (sq >= 1 && sq <= 6) tt.p[t++] = (a+2)*25 + (b+2)*5 + (c+2);
            }
    return tt;
}
__device__ const TapTable TAPS = make_taps();

// ============================================================
// Kernel 1: build scaled structured weights + fused sc matrices
// ============================================================
__global__ void prep_kernel(const float* __restrict__ wt, const float* __restrict__ wsc0,
                            const float* __restrict__ wsc1, float* __restrict__ wbuf,
                            float* __restrict__ vtab, float* __restrict__ A0,
                            float* __restrict__ A1) {
    int p = blockIdx.x;
    int dx = p / 25 - 2, dy = (p / 5) % 5 - 2, dz = p % 5 - 2;
    double d = sqrt((double)(dx*dx + dy*dy + dz*dz));
    const double step = 2.5 / 9.0;
    const double cst = 1.14136 * exp(2.0);
    float emb[8];
#pragma unroll
    for (int r = 0; r < 8; r++) {
        double t = (d - (double)(r + 1) * step) / step;
        double tt = t * t;
        emb[r] = (tt < 1.0) ? (float)(cst * exp(-2.0 / (1.0 - tt))) : 0.0f;
    }
    if (threadIdx.x == 0) {
        float inv = (d > 0.0) ? (float)(sqrt(3.0) / d) : 0.0f;
        vtab[p*4+0] = dx * inv; vtab[p*4+1] = dy * inv;
        vtab[p*4+2] = dz * inv; vtab[p*4+3] = 0.0f;
    }
    const float ALPHA = 0.14433756729740643f;   // 1/sqrt(48)
    for (int q = threadIdx.x; q < 2304; q += blockDim.x) {
        float acc = 0.0f;
#pragma unroll
        for (int r = 0; r < 8; r++) acc = fmaf(emb[r], wt[r*2304 + q], acc);
        acc *= (1.0f / 125.0f);
        float val = acc * ((q < 1792) ? ALPHA : (1.0f / 12.0f));
        wbuf[p*2304 + q] = val;
        if (p == 62) {  // center tap: val==0 (EMB(0)=0); fold sc matrices
            if (q < 1024)                   A0[q]        = wsc0[q] * 0.17677669529663687f + val;
            else if (q >= 1536 && q < 1792) A1[q-1536]   = wsc1[q-1536] * 0.25f + val;
        }
    }
}

// ============================================================
// Kernel 2: scatter (two-pass LDS histogram, padded global atomics)
// ============================================================
__global__ __launch_bounds__(256) void scatter_kernel(const int* __restrict__ coords,
        int* __restrict__ vol, int* __restrict__ rcnt_pad, int2* __restrict__ plist) {
    __shared__ int hist[216];
    __shared__ int rbase[216];
    for (int i = threadIdx.x; i < 216; i += 256) hist[i] = 0;
    __syncthreads();
    for (int n = blockIdx.x * 256 + threadIdx.x; n < N_PTS; n += 65536) {
        int x = coords[n*3], y = coords[n*3+1], z = coords[n*3+2];
        vol[(x * GRIDL + y) * GRIDL + z] = n;
        int r = (x >> 5) * 36 + (y >> 5) * 6 + (z >> 5);
        atomicAdd(&hist[r], 1);
    }
    __syncthreads();
    if (threadIdx.x < 216) {
        int c = hist[threadIdx.x];
        rbase[threadIdx.x] = c ? atomicAdd(&rcnt_pad[threadIdx.x * 32], c) : 0;
        hist[threadIdx.x] = 0;   // reuse as cursor
    }
    __syncthreads();
    for (int n = blockIdx.x * 256 + threadIdx.x; n < N_PTS; n += 65536) {
        int x = coords[n*3], y = coords[n*3+1], z = coords[n*3+2];
        int r = (x >> 5) * 36 + (y >> 5) * 6 + (z >> 5);
        int j = rbase[r] + atomicAdd(&hist[r], 1);
        if (j < RCAP) plist[r * RCAP + j] = make_int2(n, (x << 16) | (y << 8) | z);
    }
}

// ============================================================
// Kernel 3: enumerate hits. Grid 216*NSLICE blocks of 128 threads; hits
// append to per-tap LDS stage (20 KB), one padded global atomic per
// (block,tap) reserves bin space, coalesced copy-out (4 taps x 32 lanes).
// Bins carry (n, nb).
// ============================================================
__global__ __launch_bounds__(128) void enum_kernel(const int* __restrict__ vol,
        const int* __restrict__ rcnt_pad, const int2* __restrict__ plist,
        int* __restrict__ bcnt_pad, int2* __restrict__ bins) {
    int r = blockIdx.x / NSLICE, s = blockIdx.x % NSLICE;
    int cnt = min(rcnt_pad[r * 32], RCAP);
    int lo = s * 128, hi = min(cnt, lo + 128);
    if (lo >= hi) return;                      // block-uniform exit
    __shared__ int2 stage[80][SCAP];           // 20,480 B
    __shared__ int hist[80];
    __shared__ int tbase[80];
    if (threadIdx.x < 80) hist[threadIdx.x] = 0;
    __syncthreads();

    int idx = lo + threadIdx.x;
    bool act = idx < hi;
    int n = -1, x = 0, y = 0, z = 0;
    if (act) {
        int2 e = plist[r * RCAP + idx];
        n = e.x; x = e.y >> 16; y = (e.y >> 8) & 255; z = e.y & 255;
    }
    int t = 0;
#pragma unroll
    for (int a = -2; a <= 2; a++)
#pragma unroll
    for (int b = -2; b <= 2; b++)
#pragma unroll
    for (int c = -2; c <= 2; c++) {
        int sq = a*a + b*b + c*c;
        if (sq < 1 || sq > 6) continue;        // dead tap: K==0
        int cx = x + a, cy = y + b, cz = z + c;
        if (act && ((unsigned)cx < 192u) && ((unsigned)cy < 192u) && ((unsigned)cz < 192u)) {
            int nb = vol[(cx * GRIDL + cy) * GRIDL + cz];
            if (nb >= 0) {
                int j = atomicAdd(&hist[t], 1);
                if (j < SCAP) stage[t][j] = make_int2(n, nb);
            }
        }
        t++;
    }
    __syncthreads();
    if (threadIdx.x < 80) {
        int c = min(hist[threadIdx.x], SCAP);
        tbase[threadIdx.x] = c ? atomicAdd(&bcnt_pad[TAPS.p[threadIdx.x] * 32], c) : 0;
    }
    __syncthreads();
    // coalesced copy-out: 4 tap-groups in parallel, 20 taps each
    int g = threadIdx.x >> 5, l = threadIdx.x & 31;
    for (int q = 0; q < 20; q++) {
        int t2 = g * 20 + q;
        int c = min(hist[t2], SCAP);
        if (l < c) {
            int pos = tbase[t2] + l;
            if (pos < CAP) bins[TAPS.p[t2] * CAP + pos] = stage[t2][l];
        }
    }
}

// ============================================================
// Kernel 4: out[n] = sc(feats[n])  (fully initializes d_out)
// ============================================================
__global__ __launch_bounds__(256) void sc_self_kernel(const float* __restrict__ feats,
        const float* __restrict__ A0, const float* __restrict__ A1,
        float* __restrict__ out) {
    __shared__ __align__(16) float sA0[1024];
    __shared__ __align__(16) float sA1[256];
    for (int i = threadIdx.x; i < 1024; i += 256) sA0[i] = A0[i];
    if (threadIdx.x < 256) sA1[threadIdx.x] = A1[threadIdx.x];
    __syncthreads();
    int n = blockIdx.x * 256 + threadIdx.x;
    if (n >= N_PTS) return;
    const float4* fr = (const float4*)(feats + (size_t)n * 80);
    float4* orow = (float4*)(out + (size_t)n * 80);
    float f0[32];
#pragma unroll
    for (int j = 0; j < 8; j++) {
        float4 t = fr[j];
        f0[4*j] = t.x; f0[4*j+1] = t.y; f0[4*j+2] = t.z; f0[4*j+3] = t.w;
    }
    float a0[32];
#pragma unroll
    for (int k = 0; k < 32; k++) a0[k] = 0.0f;
#pragma unroll
    for (int i = 0; i < 32; i++) {
        float fv = f0[i];
#pragma unroll
        for (int k4 = 0; k4 < 8; k4++) {
            float4 w = ((const float4*)sA0)[i*8 + k4];
            a0[4*k4]   = fmaf(fv, w.x, a0[4*k4]);
            a0[4*k4+1] = fmaf(fv, w.y, a0[4*k4+1]);
            a0[4*k4+2] = fmaf(fv, w.z, a0[4*k4+2]);
            a0[4*k4+3] = fmaf(fv, w.w, a0[4*k4+3]);
        }
    }
#pragma unroll
    for (int j = 0; j < 8; j++) orow[j] = make_float4(a0[4*j], a0[4*j+1], a0[4*j+2], a0[4*j+3]);
    float f1[48];
#pragma unroll
    for (int j = 0; j < 12; j++) {
        float4 t = fr[8 + j];
        f1[4*j] = t.x; f1[4*j+1] = t.y; f1[4*j+2] = t.z; f1[4*j+3] = t.w;
    }
    float a1[48];
#pragma unroll
    for (int k = 0; k < 48; k++) a1[k] = 0.0f;
#pragma unroll
    for (int i = 0; i < 16; i++) {
        float fm0 = f1[3*i], fm1 = f1[3*i+1], fm2 = f1[3*i+2];
#pragma unroll
        for (int k4 = 0; k4 < 4; k4++) {
            float4 w = ((const float4*)sA1)[i*4 + k4];
            const float* wp = (const float*)&w;
#pragma unroll
            for (int kk = 0; kk < 4; kk++) {
                int k = 4*k4 + kk;
                a1[3*k]   = fmaf(fm0, wp[kk], a1[3*k]);
                a1[3*k+1] = fmaf(fm1, wp[kk], a1[3*k+1]);
                a1[3*k+2] = fmaf(fm2, wp[kk], a1[3*k+2]);
            }
        }
    }
#pragma unroll
    for (int j = 0; j < 12; j++) orow[8+j] = make_float4(a1[4*j], a1[4*j+1], a1[4*j+2], a1[4*j+3]);
}

// ============================================================
// Kernel 5: per-tap structured apply. R4 flush structure (LDS transpose,
// row-coalesced atomics) but ystage shrunk to [2][32][81] with two-phase
// flush: LDS 30.5 KB -> 5 blocks/CU (was 3).
// ============================================================
__global__ __launch_bounds__(128) void bin_kernel(const float* __restrict__ feats,
        const float* __restrict__ wbuf, const float* __restrict__ vtab,
        const int* __restrict__ bcnt_pad, const int2* __restrict__ bins,
        float* __restrict__ out) {
    int p = blockIdx.x >> 4;
    int chunk = blockIdx.x & 15;
    int cnt = min(bcnt_pad[p * 32], CAP);
    int start = chunk * 512;
    if (start >= cnt) return;

    __shared__ __align__(16) float sW[2304];
    __shared__ float sv[4];
    __shared__ float ys[2][32][81];     // 20,736 B
    __shared__ int   dst[2][64];

    for (int i = threadIdx.x; i < 2304; i += 128) sW[i] = wbuf[p*2304 + i];
    if (threadIdx.x < 4) sv[threadIdx.x] = vtab[p*4 + threadIdx.x];
    __syncthreads();

    int wv = threadIdx.x >> 6, lane = threadIdx.x & 63;
    const float4* sW1 = (const float4*)sW;            // [32][8]
    const float4* sW2 = (const float4*)(sW + 1024);   // [32][4]
    const float4* sW3 = (const float4*)(sW + 1536);   // [16][4]
    const float4* sW4 = (const float4*)(sW + 1792);   // [16][8]
    float v0 = sv[0], v1 = sv[1], v2 = sv[2];

    for (int it = 0; it < 4; it++) {
        int h = start + it * 128 + threadIdx.x;
        bool act = h < cnt;
        int n = -1, nb = 0;
        if (act) { int2 e = bins[p*CAP + h]; n = e.x; nb = e.y; }

        const float4* fr = (const float4*)(feats + (size_t)nb * 80);
        float f0[32], f1[48];
#pragma unroll
        for (int j = 0; j < 8; j++) {
            float4 t = fr[j];
            f0[4*j] = t.x; f0[4*j+1] = t.y; f0[4*j+2] = t.z; f0[4*j+3] = t.w;
        }
#pragma unroll
        for (int j = 0; j < 12; j++) {
            float4 t = fr[8 + j];
            f1[4*j] = t.x; f1[4*j+1] = t.y; f1[4*j+2] = t.z; f1[4*j+3] = t.w;
        }
        float g[16];
#pragma unroll
        for (int i = 0; i < 16; i++)
            g[i] = f1[3*i]*v0 + f1[3*i+1]*v1 + f1[3*i+2]*v2;

        float a0[32], cc[16];
#pragma unroll
        for (int k = 0; k < 32; k++) a0[k] = 0.0f;
#pragma unroll
        for (int k = 0; k < 16; k++) cc[k] = 0.0f;
#pragma unroll
        for (int i = 0; i < 32; i++) {
            float fv = f0[i];
#pragma unroll
            for (int k4 = 0; k4 < 8; k4++) {
                float4 w = sW1[i*8 + k4];
                a0[4*k4]   = fmaf(fv, w.x, a0[4*k4]);
                a0[4*k4+1] = fmaf(fv, w.y, a0[4*k4+1]);
                a0[4*k4+2] = fmaf(fv, w.z, a0[4*k4+2]);
                a0[4*k4+3] = fmaf(fv, w.w, a0[4*k4+3]);
            }
#pragma unroll
            for (int k4 = 0; k4 < 4; k4++) {
                float4 w = sW2[i*4 + k4];
                cc[4*k4]   = fmaf(fv, w.x, cc[4*k4]);
                cc[4*k4+1] = fmaf(fv, w.y, cc[4*k4+1]);
                cc[4*k4+2] = fmaf(fv, w.z, cc[4*k4+2]);
                cc[4*k4+3] = fmaf(fv, w.w, cc[4*k4+3]);
            }
        }
#pragma unroll
        for (int i = 0; i < 16; i++) {
            float gv = g[i];
#pragma unroll
            for (int k4 = 0; k4 < 8; k4++) {
                float4 w = sW4[i*8 + k4];
                a0[4*k4]   = fmaf(gv, w.x, a0[4*k4]);
                a0[4*k4+1] = fmaf(gv, w.y, a0[4*k4+1]);
                a0[4*k4+2] = fmaf(gv, w.z, a0[4*k4+2]);
                a0[4*k4+3] = fmaf(gv, w.w, a0[4*k4+3]);
            }
        }
        float a1[48];
#pragma unroll
        for (int k = 0; k < 16; k++) {
            a1[3*k] = v0 * cc[k]; a1[3*k+1] = v1 * cc[k]; a1[3*k+2] = v2 * cc[k];
        }
#pragma unroll
        for (int i = 0; i < 16; i++) {
            float fm0 = f1[3*i], fm1 = f1[3*i+1], fm2 = f1[3*i+2];
#pragma unroll
            for (int k4 = 0; k4 < 4; k4++) {
                float4 w = sW3[i*4 + k4];
                const float* wp = (const float*)&w;
#pragma unroll
                for (int kk = 0; kk < 4; kk++) {
                    int k = 4*k4 + kk;
                    a1[3*k]   = fmaf(fm0, wp[kk], a1[3*k]);
                    a1[3*k+1] = fmaf(fm1, wp[kk], a1[3*k+1]);
                    a1[3*k+2] = fmaf(fm2, wp[kk], a1[3*k+2]);
                }
            }
        }
        dst[wv][lane] = act ? n : -1;

        // two-phase transpose flush through 32-row LDS slice
#pragma unroll
        for (int ph = 0; ph < 2; ph++) {
            if ((lane >> 5) == ph) {
                int rr = lane & 31;
#pragma unroll
                for (int k = 0; k < 32; k++) ys[wv][rr][k] = a0[k];
#pragma unroll
                for (int k = 0; k < 48; k++) ys[wv][rr][32 + k] = a1[k];
            }
            __syncthreads();
            for (int h2 = 0; h2 < 32; h2++) {
                int nn = dst[wv][ph * 32 + h2];   // wave-uniform
                if (nn < 0) continue;
                float* orow = out + (size_t)nn * 80;
                unsafeAtomicAdd(orow + lane, ys[wv][h2][lane]);
                if (lane < 16) unsafeAtomicAdd(orow + 64 + lane, ys[wv][h2][64 + lane]);
            }
            __syncthreads();
        }
    }
}

extern "C" void kernel_launch(void* const* d_in, const int* in_sizes, int n_in,
                              void* d_out, int out_size, void* d_ws, size_t ws_size,
                              hipStream_t stream) {
    const float* feats = (const float*)d_in[0];
    const float* wt    = (const float*)d_in[1];
    const float* wsc0  = (const float*)d_in[2];
    const float* wsc1  = (const float*)d_in[3];
    const int*   coords= (const int*)d_in[4];
    float* out = (float*)d_out;
    char* ws = (char*)d_ws;

    int*   vol      = (int*)(ws + VOL_OFF);
    int2*  bins     = (int2*)(ws + BINS_OFF);
    int*   bcnt_pad = (int*)(ws + BCNT_OFF);
    int*   rcnt_pad = (int*)(ws + RCNT_OFF);
    int2*  plist    = (int2*)(ws + PLIST_OFF);
    float* wbuf     = (float*)(ws + WBUF_OFF);
    float* vtab     = (float*)(ws + VTAB_OFF);
    float* A0       = (float*)(ws + A0_OFF);
    float* A1       = (float*)(ws + A1_OFF);

    hipMemsetAsync(vol, 0xFF, VOL_BYTES, stream);            // -1 everywhere
    hipMemsetAsync(bcnt_pad, 0, 16000 + 27648, stream);      // bcnt + rcnt

    prep_kernel<<<125, 256, 0, stream>>>(wt, wsc0, wsc1, wbuf, vtab, A0, A1);
    scatter_kernel<<<256, 256, 0, stream>>>(coords, vol, rcnt_pad, plist);
    enum_kernel<<<NREG * NSLICE, 128, 0, stream>>>(vol, rcnt_pad, plist, bcnt_pad, bins);
    sc_self_kernel<<<(N_PTS + 255) / 256, 256, 0, stream>>>(feats, A0, A1, out);
    bin_kernel<<<125 * 16, 128, 0, stream>>>(feats, wbuf, vtab, bcnt_pad, bins, out);
}